// Round 1
// baseline (223.218 us; speedup 1.0000x reference)
//
#include <hip/hip_runtime.h>
#include <cstddef>

// Problem constants
static constexpr int TT = 64;    // decoder steps
static constexpr int BB = 8;     // batch
static constexpr int SS = 512;   // source length
static constexpr int HH = 512;   // hidden

__device__ __forceinline__ float fast_tanh(float x) {
  // tanh(x) = 1 - 2/(exp(2x)+1); exp via v_exp_f32, rcp via v_rcp_f32.
  // Saturates correctly for |x| large (rcp(inf)=0 -> 1; exp->0 -> -1).
  float e = __expf(2.0f * x);
  float r = __builtin_amdgcn_rcpf(e + 1.0f);
  return 1.0f - 2.0f * r;
}

// ---------------------------------------------------------------------------
// K1: encp[b,s,h] = tanh(enc[s,b,h] + cov[b,s]*wcov[h])
// ---------------------------------------------------------------------------
__global__ __launch_bounds__(256)
void k_enc(const float* __restrict__ enc, const float* __restrict__ cov,
           const float* __restrict__ wcov, float* __restrict__ encp) {
  const int idx = blockIdx.x * 256 + threadIdx.x;   // over B*S*H = 2097152
  const int h  = idx & (HH - 1);
  const int bs = idx >> 9;          // b*S + s
  const int s  = bs & (SS - 1);
  const int b  = bs >> 9;
  const float x = enc[(s * BB + b) * HH + h] + cov[bs] * wcov[h];
  encp[idx] = fast_tanh(x);
}

// ---------------------------------------------------------------------------
// Generic fp32 GEMM: C[M,512] = A[M,K] * W[K,512], K-split into partials.
// BM=64, BN=128, BK=16, 256 threads, 4x8 microtile (n split as tx*4 and 64+tx*4
// to keep LDS reads 2-way-conflict-free).
// MODE 0: A row r -> dec[t=r%64, b=r/64, k]         (for a1)
// MODE 1: A row r -> A0[r*K + k]                    (for a2, A0=encp)
// MODE 2: A row r -> k<512 ? c[r,k] : dec[t,b,k-512](for out)
// Cout[(z*M + r)*512 + n]
// ---------------------------------------------------------------------------
static constexpr int BM = 64;
static constexpr int BN = 128;
static constexpr int BK = 16;

template<int MODE, int KTOT, int KSPLIT>
__global__ __launch_bounds__(256)
void k_gemm(const float* __restrict__ A0, const float* __restrict__ A1,
            const float* __restrict__ W, float* __restrict__ Cout) {
  constexpr int KC = KTOT / KSPLIT;
  const int tid = threadIdx.x;
  const int n0 = blockIdx.x * BN;
  const int m0 = blockIdx.y * BM;
  const int k0 = blockIdx.z * KC;
  const int Mtot = gridDim.y * BM;

  __shared__ __align__(16) float As[BK][BM + 4];
  __shared__ __align__(16) float Ws[BK][BN + 4];

  const int tx = tid & 15;   // n-dir
  const int ty = tid >> 4;   // m-dir

  // A staging: each thread loads one float4 along k
  const int lam = tid >> 2;          // 0..63 (m)
  const int lak = (tid & 3) * 4;     // 0,4,8,12 (k)
  // W staging: each thread loads two float4 rows (k and k+8)
  const int lwn = (tid & 31) * 4;    // 0..124
  const int lwk = tid >> 5;          // 0..7

  float acc[4][8];
#pragma unroll
  for (int i = 0; i < 4; ++i)
#pragma unroll
    for (int j = 0; j < 8; ++j) acc[i][j] = 0.0f;

  for (int kt = 0; kt < KC; kt += BK) {
    const int kg = k0 + kt;
    // ---- load A tile (64m x 16k) ----
    {
      const int m = m0 + lam;
      const int kk = kg + lak;
      float4 av;
      if (MODE == 0) {
        av = *(const float4*)(A0 + (size_t)(m & 63) * (BB * HH) + (m >> 6) * HH + kk);
      } else if (MODE == 1) {
        av = *(const float4*)(A0 + (size_t)m * KTOT + kk);
      } else {
        if (kk < HH)
          av = *(const float4*)(A0 + (size_t)m * HH + kk);
        else
          av = *(const float4*)(A1 + (size_t)(m & 63) * (BB * HH) + (m >> 6) * HH + (kk - HH));
      }
      As[lak + 0][lam] = av.x;
      As[lak + 1][lam] = av.y;
      As[lak + 2][lam] = av.z;
      As[lak + 3][lam] = av.w;
    }
    // ---- load W tile (16k x 128n) ----
    {
      const float4 w0 = *(const float4*)(W + (size_t)(kg + lwk) * 512 + n0 + lwn);
      const float4 w1 = *(const float4*)(W + (size_t)(kg + lwk + 8) * 512 + n0 + lwn);
      *(float4*)&Ws[lwk][lwn] = w0;
      *(float4*)&Ws[lwk + 8][lwn] = w1;
    }
    __syncthreads();
#pragma unroll
    for (int k = 0; k < BK; ++k) {
      const float4 a  = *(const float4*)&As[k][ty * 4];
      const float4 w0 = *(const float4*)&Ws[k][tx * 4];
      const float4 w1 = *(const float4*)&Ws[k][tx * 4 + 64];
      const float av_[4] = {a.x, a.y, a.z, a.w};
      const float wv[8]  = {w0.x, w0.y, w0.z, w0.w, w1.x, w1.y, w1.z, w1.w};
#pragma unroll
      for (int i = 0; i < 4; ++i)
#pragma unroll
        for (int j = 0; j < 8; ++j)
          acc[i][j] = fmaf(av_[i], wv[j], acc[i][j]);
    }
    __syncthreads();
  }

#pragma unroll
  for (int i = 0; i < 4; ++i) {
    const int m = m0 + ty * 4 + i;
    float* row = Cout + ((size_t)blockIdx.z * Mtot + m) * 512 + n0;
    *(float4*)(row + tx * 4)      = make_float4(acc[i][0], acc[i][1], acc[i][2], acc[i][3]);
    *(float4*)(row + 64 + tx * 4) = make_float4(acc[i][4], acc[i][5], acc[i][6], acc[i][7]);
  }
}

// ---------------------------------------------------------------------------
// Reduce K-split partials (+ optional bias), optional transpose-scatter to
// out[(t*B+b)*H+n] for the final attn_h.
// ---------------------------------------------------------------------------
template<int KSPLIT, bool SCATTER>
__global__ __launch_bounds__(256)
void k_reduce(const float* __restrict__ part, const float* __restrict__ bias,
              float* __restrict__ outp, int Mtot) {
  const int idx = blockIdx.x * 256 + threadIdx.x;   // over Mtot*512
  const int n = idx & 511;
  const int r = idx >> 9;
  float acc = bias ? bias[n] : 0.0f;
#pragma unroll
  for (int p = 0; p < KSPLIT; ++p)
    acc += part[((size_t)p * Mtot + r) * 512 + n];
  if (SCATTER) {
    const int b = r >> 6, t = r & 63;
    outp[(t * BB + b) * HH + n] = acc;
  } else {
    outp[idx] = acc;
  }
}

// ---------------------------------------------------------------------------
// Fused scores + softmax + context.
// Block: (b, t-pair), 512 threads (8 waves).
// Scores lane layout: lane = 4*sl + hq; wave handles 16 s, 4 h-quads of float4
//   -> a2 reads are 16 contiguous 64B segments per wave instruction.
// Then block softmax over S=512, align written to d_out, and context
// c[b,t,h] = sum_s align*encp computed with h=tid (coalesced encp reads).
// ---------------------------------------------------------------------------
__global__ __launch_bounds__(512)
void k_attn(const float* __restrict__ a1, const float* __restrict__ a2,
            const float* __restrict__ encp, const float* __restrict__ v,
            float* __restrict__ align_out, float* __restrict__ cbuf) {
  const int b  = blockIdx.x & 7;          // XCD-affine: a2[b]+encp[b] stay in one L2
  const int t0 = (blockIdx.x >> 3) * 2;
  const int tid = threadIdx.x;
  const int wave = tid >> 6, lane = tid & 63;
  const int hq = lane & 3, sl = lane >> 2;

  __shared__ __align__(16) float a1s[2][HH];
  __shared__ __align__(16) float vs[HH];
  __shared__ __align__(16) float sc[2][SS];
  __shared__ float red[2][8];

  a1s[0][tid] = a1[(size_t)(b * TT + t0) * HH + tid];
  a1s[1][tid] = a1[(size_t)(b * TT + t0 + 1) * HH + tid];
  vs[tid] = v[tid];
  __syncthreads();

  // ---- scores ----
  for (int pass = 0; pass < 4; ++pass) {
    const int s = pass * 128 + wave * 16 + sl;
    const float* arow = a2 + (size_t)(b * SS + s) * HH;
    float acc0 = 0.f, acc1 = 0.f;
#pragma unroll 4
    for (int it = 0; it < 32; ++it) {
      const int h = it * 16 + hq * 4;
      const float4 a2v = *(const float4*)(arow + h);
      const float4 p0  = *(const float4*)&a1s[0][h];
      const float4 p1  = *(const float4*)&a1s[1][h];
      const float4 vv  = *(const float4*)&vs[h];
      acc0 = fmaf(fast_tanh(p0.x + a2v.x), vv.x, acc0);
      acc0 = fmaf(fast_tanh(p0.y + a2v.y), vv.y, acc0);
      acc0 = fmaf(fast_tanh(p0.z + a2v.z), vv.z, acc0);
      acc0 = fmaf(fast_tanh(p0.w + a2v.w), vv.w, acc0);
      acc1 = fmaf(fast_tanh(p1.x + a2v.x), vv.x, acc1);
      acc1 = fmaf(fast_tanh(p1.y + a2v.y), vv.y, acc1);
      acc1 = fmaf(fast_tanh(p1.z + a2v.z), vv.z, acc1);
      acc1 = fmaf(fast_tanh(p1.w + a2v.w), vv.w, acc1);
    }
    // reduce over the 4 h-quads (lanes differing in bits 0..1)
    acc0 += __shfl_xor(acc0, 1); acc0 += __shfl_xor(acc0, 2);
    acc1 += __shfl_xor(acc1, 1); acc1 += __shfl_xor(acc1, 2);
    if (hq == 0) { sc[0][s] = acc0; sc[1][s] = acc1; }
  }
  __syncthreads();

  // ---- softmax over s (thread tid owns s=tid) ----
  const float x0 = sc[0][tid], x1 = sc[1][tid];
  float m0 = x0, m1 = x1;
#pragma unroll
  for (int off = 32; off; off >>= 1) {
    m0 = fmaxf(m0, __shfl_xor(m0, off));
    m1 = fmaxf(m1, __shfl_xor(m1, off));
  }
  if (lane == 0) { red[0][wave] = m0; red[1][wave] = m1; }
  __syncthreads();
  m0 = red[0][0]; m1 = red[1][0];
#pragma unroll
  for (int w = 1; w < 8; ++w) { m0 = fmaxf(m0, red[0][w]); m1 = fmaxf(m1, red[1][w]); }
  __syncthreads();   // everyone done reading red before reuse
  const float e0 = __expf(x0 - m0), e1 = __expf(x1 - m1);
  float s0 = e0, s1 = e1;
#pragma unroll
  for (int off = 32; off; off >>= 1) {
    s0 += __shfl_xor(s0, off);
    s1 += __shfl_xor(s1, off);
  }
  if (lane == 0) { red[0][wave] = s0; red[1][wave] = s1; }
  __syncthreads();
  float sum0 = 0.f, sum1 = 0.f;
#pragma unroll
  for (int w = 0; w < 8; ++w) { sum0 += red[0][w]; sum1 += red[1][w]; }
  const float al0 = e0 * __builtin_amdgcn_rcpf(sum0);
  const float al1 = e1 * __builtin_amdgcn_rcpf(sum1);

  // align output layout: [T,B,S]
  align_out[(size_t)(t0 + 0) * BB * SS + b * SS + tid] = al0;
  align_out[(size_t)(t0 + 1) * BB * SS + b * SS + tid] = al1;

  sc[0][tid] = al0;
  sc[1][tid] = al1;
  __syncthreads();

  // ---- context: c[b,t,h] = sum_s align[s] * encp[b,s,h], h = tid ----
  float c0 = 0.f, c1 = 0.f;
  const float* ep = encp + (size_t)b * SS * HH + tid;
#pragma unroll 8
  for (int s2 = 0; s2 < SS; ++s2) {
    const float ev = ep[(size_t)s2 * HH];
    c0 = fmaf(sc[0][s2], ev, c0);
    c1 = fmaf(sc[1][s2], ev, c1);
  }
  cbuf[(size_t)(b * TT + t0) * HH + tid] = c0;
  cbuf[(size_t)(b * TT + t0 + 1) * HH + tid] = c1;
}

// ---------------------------------------------------------------------------
// Launch
// ---------------------------------------------------------------------------
extern "C" void kernel_launch(void* const* d_in, const int* in_sizes, int n_in,
                              void* d_out, int out_size, void* d_ws, size_t ws_size,
                              hipStream_t stream) {
  const float* dec  = (const float*)d_in[0];   // [T,B,H]
  const float* enc  = (const float*)d_in[1];   // [S,B,H]
  const float* cov  = (const float*)d_in[2];   // [B,S]
  const float* Wq   = (const float*)d_in[3];   // [H,H]
  const float* bq   = (const float*)d_in[4];   // [H]
  const float* Wc   = (const float*)d_in[5];   // [H,H]
  const float* v    = (const float*)d_in[6];   // [H]
  const float* Wo   = (const float*)d_in[7];   // [2H,H]
  const float* bo   = (const float*)d_in[8];   // [H]
  const float* wcov = (const float*)d_in[9];   // [H]

  float* out = (float*)d_out;
  float* attn_h    = out;                       // [T,B,H] = 262144
  float* align_out = out + (size_t)TT * BB * HH;  // [T,B,S] = 262144

  float* ws = (float*)d_ws;
  float* encp = ws;                    // 2,097,152 floats  [B,S,H]
  float* a2   = ws + 2097152;          // 2,097,152 floats  [B*S, H]
  float* a1b  = ws + 4194304;          //   262,144 floats  [B*T, H]
  float* cbuf = ws + 4456448;          //   262,144 floats  [B*T, H]
  float* part = ws + 4718592;          // 4,194,304 floats  (K-split partials, max 2x4096x512)

  // 1) enc' = tanh(enc + cov*wcov)
  k_enc<<<dim3((BB * SS * HH) / 256), dim3(256), 0, stream>>>(enc, cov, wcov, encp);

  // 2) a1 = dec @ Wq (+bq in reduce). K-split 8 -> 256 blocks.
  k_gemm<0, 512, 8><<<dim3(4, 8, 8), dim3(256), 0, stream>>>(dec, nullptr, Wq, part);
  k_reduce<8, false><<<dim3(1024), dim3(256), 0, stream>>>(part, bq, a1b, 512);

  // 3) a2 = encp @ Wc. K-split 2 -> 512 blocks (2/CU for latency hiding).
  k_gemm<1, 512, 2><<<dim3(4, 64, 2), dim3(256), 0, stream>>>(encp, nullptr, Wc, part);
  k_reduce<2, false><<<dim3(8192), dim3(256), 0, stream>>>(part, nullptr, a2, 4096);

  // 4) fused scores + softmax + context
  k_attn<<<dim3(256), dim3(512), 0, stream>>>(a1b, a2, encp, v, align_out, cbuf);

  // 5) attn_h = [c, dec] @ Wo + bo, scattered to [T,B,H]. K-split 8 -> 256 blocks.
  k_gemm<2, 1024, 8><<<dim3(4, 8, 8), dim3(256), 0, stream>>>(cbuf, dec, Wo, part);
  k_reduce<8, true><<<dim3(1024), dim3(256), 0, stream>>>(part, bo, attn_h, 512);
}

// Round 2
// 176.489 us; speedup vs baseline: 1.2648x; 1.2648x over previous
//
#include <hip/hip_runtime.h>
#include <cstddef>

static constexpr int TT = 64;    // decoder steps
static constexpr int BB = 8;     // batch
static constexpr int SS = 512;   // source length
static constexpr int HH = 512;   // hidden

typedef __attribute__((ext_vector_type(8))) short bf16x8;
typedef __attribute__((ext_vector_type(4))) float f32x4;

__device__ __forceinline__ float fast_tanh(float x) {
  // tanh(x) = 1 - 2/(exp(2x)+1). exp/rcp quarter-rate but exact enough.
  float e = __expf(2.0f * x);
  float r = __builtin_amdgcn_rcpf(e + 1.0f);
  return 1.0f - 2.0f * r;
}

__device__ __forceinline__ unsigned short f2bf(float f) {
  unsigned u = __float_as_uint(f);
  unsigned r = (u + 0x7FFFu + ((u >> 16) & 1u)) >> 16;   // RNE
  return (unsigned short)r;
}
__device__ __forceinline__ float bf2f(unsigned short s) {
  return __uint_as_float(((unsigned)s) << 16);
}

// ---------------------------------------------------------------------------
// p_wt: WT[n][k] (bf16) = W[k][n] (fp32).  W row stride = 512 (N) always.
// Block = 32x32 tile; grid (N/32, K/32); 256 threads.
// ---------------------------------------------------------------------------
__global__ __launch_bounds__(256)
void p_wt(const float* __restrict__ W, unsigned short* __restrict__ WT, int KT) {
  __shared__ float tile[32][33];
  const int n0 = blockIdx.x * 32, k0 = blockIdx.y * 32;
  const int r = threadIdx.x >> 3, c4 = (threadIdx.x & 7) * 4;
  const float4 w = *(const float4*)(W + (size_t)(k0 + r) * 512 + n0 + c4);
  tile[r][c4 + 0] = w.x; tile[r][c4 + 1] = w.y;
  tile[r][c4 + 2] = w.z; tile[r][c4 + 3] = w.w;
  __syncthreads();
  unsigned short* o = WT + (size_t)(n0 + r) * KT + k0 + c4;
#pragma unroll
  for (int i = 0; i < 4; ++i) o[i] = f2bf(tile[c4 + i][r]);
}

// ---------------------------------------------------------------------------
// p_dec: decb[(b*64+t)*512+h] = bf16(dec[t,b,h]); also fills right half of
// concatb[(b*64+t)*1024 + 512 + h].
// ---------------------------------------------------------------------------
__global__ __launch_bounds__(256)
void p_dec(const float* __restrict__ dec, unsigned short* __restrict__ decb,
           unsigned short* __restrict__ concatb) {
  const int idx = blockIdx.x * 256 + threadIdx.x;   // over 512*512
  const int h = idx & 511, m = idx >> 9;            // m = b*64+t
  const int b = m >> 6, t = m & 63;
  const unsigned short v = f2bf(dec[(size_t)(t * BB + b) * HH + h]);
  decb[idx] = v;
  concatb[(size_t)m * 1024 + 512 + h] = v;
}

// ---------------------------------------------------------------------------
// k_enc: encpb[b,s,h] = bf16(tanh(enc[s,b,h] + cov[b,s]*wcov[h]))
// ---------------------------------------------------------------------------
__global__ __launch_bounds__(256)
void k_enc(const float* __restrict__ enc, const float* __restrict__ cov,
           const float* __restrict__ wcov, unsigned short* __restrict__ encpb) {
  const int idx = blockIdx.x * 256 + threadIdx.x;   // over B*S*H
  const int h = idx & 511;
  const int bs = idx >> 9;
  const int s = bs & 511, b = bs >> 9;
  const float x = enc[(size_t)(s * BB + b) * HH + h] + cov[bs] * wcov[h];
  encpb[idx] = f2bf(fast_tanh(x));
}

// ---------------------------------------------------------------------------
// bf16 MFMA GEMM: C[M,512] = A[M,K] (bf16, lda) * W (as WT[n][k] bf16, ld=KTOT)
// Tile 64x64, BK=64, 256 threads = 4 waves; wave w owns rows [w*16, w*16+16).
// mfma_f32_16x16x32_bf16: A frag lane: m=lane&15, k=(lane>>4)*8+j.
//                         C/D: col=lane&15, row=(lane>>4)*4+reg.
// EPI: 0 plain fp32 C[m*512+n]; 1 +bias; 2 +bias & scatter m=b*64+t -> [t,b].
// ---------------------------------------------------------------------------
template<int KTOT, int EPI>
__global__ __launch_bounds__(256)
void k_mgemm(const unsigned short* __restrict__ A, int lda,
             const unsigned short* __restrict__ BT,
             const float* __restrict__ bias, float* __restrict__ C) {
  __shared__ unsigned short As[64][72];   // row 144 B: 16B-aligned, conflict-free frags
  __shared__ unsigned short Bs[64][72];
  const int tid = threadIdx.x;
  const int w = tid >> 6, lane = tid & 63;
  const int n0 = blockIdx.x * 64, m0 = blockIdx.y * 64;

  f32x4 acc[4] = {};

  const int lr = tid >> 2, lk = (tid & 3) * 16;
  const int fm = w * 16 + (lane & 15);
  const int fk = (lane >> 4) * 8;

  for (int k0 = 0; k0 < KTOT; k0 += 64) {
    const uint4* ga = (const uint4*)(A + (size_t)(m0 + lr) * lda + k0 + lk);
    const uint4* gb = (const uint4*)(BT + (size_t)(n0 + lr) * KTOT + k0 + lk);
    uint4 a0 = ga[0], a1 = ga[1];
    uint4 b0 = gb[0], b1 = gb[1];
    *(uint4*)&As[lr][lk] = a0;
    *(uint4*)&As[lr][lk + 8] = a1;
    *(uint4*)&Bs[lr][lk] = b0;
    *(uint4*)&Bs[lr][lk + 8] = b1;
    __syncthreads();
#pragma unroll
    for (int ks = 0; ks < 2; ++ks) {
      bf16x8 af = *(const bf16x8*)&As[fm][ks * 32 + fk];
#pragma unroll
      for (int j = 0; j < 4; ++j) {
        bf16x8 bf = *(const bf16x8*)&Bs[j * 16 + (lane & 15)][ks * 32 + fk];
        acc[j] = __builtin_amdgcn_mfma_f32_16x16x32_bf16(af, bf, acc[j], 0, 0, 0);
      }
    }
    __syncthreads();
  }

  const int col = lane & 15, rq = lane >> 4;
#pragma unroll
  for (int j = 0; j < 4; ++j) {
    const int n = n0 + j * 16 + col;
    const float bv = (EPI >= 1) ? bias[n] : 0.0f;
#pragma unroll
    for (int r = 0; r < 4; ++r) {
      const int m = m0 + w * 16 + rq * 4 + r;
      const float val = acc[j][r] + bv;
      if (EPI == 2) {
        const int b = m >> 6, t = m & 63;
        C[(size_t)(t * BB + b) * 512 + n] = val;
      } else {
        C[(size_t)m * 512 + n] = val;
      }
    }
  }
}

// ---------------------------------------------------------------------------
// k_scores: raw scores sc[b,t,s] = sum_h tanh(a1[b,t,h]+a2[b,s,h]) * v[h].
// Block = (b, t-pair, 64-s-chunk): grid 8*32*8 = 2048, 256 threads (4 waves).
// Wave lane layout: sl=lane>>2 (16 s), hq=lane&3 (4 h-quads of float4).
// ---------------------------------------------------------------------------
__global__ __launch_bounds__(256)
void k_scores(const float* __restrict__ a1, const float* __restrict__ a2,
              const float* __restrict__ v, float* __restrict__ scb) {
  const int blk = blockIdx.x;
  const int b = blk & 7;                 // XCD-affine
  const int t0 = ((blk >> 3) & 31) * 2;
  const int s0 = (blk >> 8) * 64;
  const int tid = threadIdx.x;
  const int wv = tid >> 6, lane = tid & 63;
  const int hq = lane & 3, sl = lane >> 2;

  __shared__ __align__(16) float a1s[2][HH];
  __shared__ __align__(16) float vs[HH];

  a1s[0][tid] = a1[(size_t)(b * TT + t0) * HH + tid];
  a1s[0][tid + 256] = a1[(size_t)(b * TT + t0) * HH + tid + 256];
  a1s[1][tid] = a1[(size_t)(b * TT + t0 + 1) * HH + tid];
  a1s[1][tid + 256] = a1[(size_t)(b * TT + t0 + 1) * HH + tid + 256];
  vs[tid] = v[tid];
  vs[tid + 256] = v[tid + 256];
  __syncthreads();

  const int s = s0 + wv * 16 + sl;
  const float* arow = a2 + (size_t)(b * SS + s) * HH;
  float acc0 = 0.f, acc1 = 0.f;
#pragma unroll 4
  for (int it = 0; it < 32; ++it) {
    const int h = it * 16 + hq * 4;
    const float4 a2v = *(const float4*)(arow + h);
    const float4 p0 = *(const float4*)&a1s[0][h];
    const float4 p1 = *(const float4*)&a1s[1][h];
    const float4 vvv = *(const float4*)&vs[h];
    acc0 = fmaf(fast_tanh(p0.x + a2v.x), vvv.x, acc0);
    acc0 = fmaf(fast_tanh(p0.y + a2v.y), vvv.y, acc0);
    acc0 = fmaf(fast_tanh(p0.z + a2v.z), vvv.z, acc0);
    acc0 = fmaf(fast_tanh(p0.w + a2v.w), vvv.w, acc0);
    acc1 = fmaf(fast_tanh(p1.x + a2v.x), vvv.x, acc1);
    acc1 = fmaf(fast_tanh(p1.y + a2v.y), vvv.y, acc1);
    acc1 = fmaf(fast_tanh(p1.z + a2v.z), vvv.z, acc1);
    acc1 = fmaf(fast_tanh(p1.w + a2v.w), vvv.w, acc1);
  }
  acc0 += __shfl_xor(acc0, 1); acc0 += __shfl_xor(acc0, 2);
  acc1 += __shfl_xor(acc1, 1); acc1 += __shfl_xor(acc1, 2);
  if (hq == 0) {
    scb[(size_t)(b * TT + t0) * SS + s] = acc0;
    scb[(size_t)(b * TT + t0 + 1) * SS + s] = acc1;
  }
}

// ---------------------------------------------------------------------------
// k_softmax_ctx: per (b, t-pair) block, 512 threads.
// Softmax over S=512 (s=tid), align -> d_out [T,B,S]; then context
// c[b,t,h] = sum_s align*encp (h=tid, encp bf16), written bf16 into concatb.
// ---------------------------------------------------------------------------
__global__ __launch_bounds__(512)
void k_softmax_ctx(const float* __restrict__ scb,
                   const unsigned short* __restrict__ encpb,
                   float* __restrict__ align_out,
                   unsigned short* __restrict__ concatb) {
  const int b = blockIdx.x & 7;
  const int t0 = (blockIdx.x >> 3) * 2;
  const int tid = threadIdx.x;
  const int wave = tid >> 6, lane = tid & 63;

  __shared__ __align__(16) float al[2][SS];
  __shared__ float red[2][8];

  const float x0 = scb[(size_t)(b * TT + t0) * SS + tid];
  const float x1 = scb[(size_t)(b * TT + t0 + 1) * SS + tid];
  float m0 = x0, m1 = x1;
#pragma unroll
  for (int off = 32; off; off >>= 1) {
    m0 = fmaxf(m0, __shfl_xor(m0, off));
    m1 = fmaxf(m1, __shfl_xor(m1, off));
  }
  if (lane == 0) { red[0][wave] = m0; red[1][wave] = m1; }
  __syncthreads();
  m0 = red[0][0]; m1 = red[1][0];
#pragma unroll
  for (int w = 1; w < 8; ++w) { m0 = fmaxf(m0, red[0][w]); m1 = fmaxf(m1, red[1][w]); }
  __syncthreads();
  const float e0 = __expf(x0 - m0), e1 = __expf(x1 - m1);
  float s0 = e0, s1 = e1;
#pragma unroll
  for (int off = 32; off; off >>= 1) {
    s0 += __shfl_xor(s0, off);
    s1 += __shfl_xor(s1, off);
  }
  if (lane == 0) { red[0][wave] = s0; red[1][wave] = s1; }
  __syncthreads();
  float sum0 = 0.f, sum1 = 0.f;
#pragma unroll
  for (int w = 0; w < 8; ++w) { sum0 += red[0][w]; sum1 += red[1][w]; }
  const float al0 = e0 * __builtin_amdgcn_rcpf(sum0);
  const float al1 = e1 * __builtin_amdgcn_rcpf(sum1);

  align_out[(size_t)(t0 + 0) * BB * SS + b * SS + tid] = al0;
  align_out[(size_t)(t0 + 1) * BB * SS + b * SS + tid] = al1;
  al[0][tid] = al0;
  al[1][tid] = al1;
  __syncthreads();

  float c0 = 0.f, c1 = 0.f;
  const unsigned short* ep = encpb + (size_t)b * SS * HH + tid;
#pragma unroll 8
  for (int s2 = 0; s2 < SS; ++s2) {
    const float ev = bf2f(ep[(size_t)s2 * HH]);
    c0 = fmaf(al[0][s2], ev, c0);
    c1 = fmaf(al[1][s2], ev, c1);
  }
  concatb[(size_t)(b * TT + t0) * 1024 + tid] = f2bf(c0);
  concatb[(size_t)(b * TT + t0 + 1) * 1024 + tid] = f2bf(c1);
}

// ---------------------------------------------------------------------------
// Launch
// ---------------------------------------------------------------------------
extern "C" void kernel_launch(void* const* d_in, const int* in_sizes, int n_in,
                              void* d_out, int out_size, void* d_ws, size_t ws_size,
                              hipStream_t stream) {
  const float* dec  = (const float*)d_in[0];
  const float* enc  = (const float*)d_in[1];
  const float* cov  = (const float*)d_in[2];
  const float* Wq   = (const float*)d_in[3];
  const float* bq   = (const float*)d_in[4];
  const float* Wc   = (const float*)d_in[5];
  const float* v    = (const float*)d_in[6];
  const float* Wo   = (const float*)d_in[7];
  const float* bo   = (const float*)d_in[8];
  const float* wcov = (const float*)d_in[9];

  float* out = (float*)d_out;
  float* attn_h    = out;                         // [T,B,H]
  float* align_out = out + (size_t)TT * BB * HH;  // [T,B,S]

  char* w = (char*)d_ws;
  const size_t MB = 1024 * 1024;
  unsigned short* encpb   = (unsigned short*)(w);            // 4 MB  [B*S, H] bf16
  unsigned short* WqT     = (unsigned short*)(w + 4 * MB);   // 0.5 MB [N][K]
  unsigned short* WcT     = (unsigned short*)(w + 5 * MB);   // 0.5 MB
  unsigned short* WoT     = (unsigned short*)(w + 6 * MB);   // 1 MB   [512][1024]
  unsigned short* decb    = (unsigned short*)(w + 7 * MB);   // 0.5 MB [b*64+t][H]
  unsigned short* concatb = (unsigned short*)(w + 8 * MB);   // 1 MB   [b*64+t][1024]
  float*          a1b     = (float*)(w + 9 * MB);            // 1 MB   [b*64+t][H]
  float*          a2      = (float*)(w + 10 * MB);           // 8 MB   [b*512+s][H]
  float*          scb     = (float*)(w + 18 * MB);           // 1 MB   [b*64+t][S]

  // Prep: weight transposes+cvt, dec reorder+cvt (also concat right half)
  p_wt<<<dim3(16, 16), 256, 0, stream>>>(Wq, WqT, 512);
  p_wt<<<dim3(16, 16), 256, 0, stream>>>(Wc, WcT, 512);
  p_wt<<<dim3(16, 32), 256, 0, stream>>>(Wo, WoT, 1024);
  p_dec<<<1024, 256, 0, stream>>>(dec, decb, concatb);
  k_enc<<<8192, 256, 0, stream>>>(enc, cov, wcov, encpb);

  // a1 = dec@Wq + bq   [512 x 512]
  k_mgemm<512, 1><<<dim3(8, 8), 256, 0, stream>>>(decb, 512, WqT, bq, a1b);
  // a2 = encp@Wc       [4096 x 512]
  k_mgemm<512, 0><<<dim3(8, 64), 256, 0, stream>>>(encpb, 512, WcT, nullptr, a2);

  // scores -> softmax+context
  k_scores<<<2048, 256, 0, stream>>>(a1b, a2, v, scb);
  k_softmax_ctx<<<256, 512, 0, stream>>>(scb, encpb, align_out, concatb);

  // attn_h = [c,dec]@Wo + bo, scattered to [T,B,H]
  k_mgemm<1024, 2><<<dim3(8, 8), 256, 0, stream>>>(concatb, 1024, WoT, bo, attn_h);
}

// Round 3
// 143.082 us; speedup vs baseline: 1.5601x; 1.2335x over previous
//
#include <hip/hip_runtime.h>
#include <cstddef>

static constexpr int TT = 64;    // decoder steps
static constexpr int BB = 8;     // batch
static constexpr int SS = 512;   // source length
static constexpr int HH = 512;   // hidden

typedef __attribute__((ext_vector_type(8))) short bf16x8;
typedef __attribute__((ext_vector_type(4))) float f32x4;

__device__ __forceinline__ float fast_tanh(float x) {
  float e = __expf(2.0f * x);
  float r = __builtin_amdgcn_rcpf(e + 1.0f);
  return 1.0f - 2.0f * r;
}
__device__ __forceinline__ unsigned short f2bf(float f) {
  unsigned u = __float_as_uint(f);
  unsigned r = (u + 0x7FFFu + ((u >> 16) & 1u)) >> 16;   // RNE
  return (unsigned short)r;
}

// ---------------------------------------------------------------------------
// k_prep — one launch for ALL preprocessing:
//  blocks [0,8192):     encpb[b,s,h] = bf16(tanh(enc[s,b,h]+cov[b,s]*wcov[h]))
//  blocks [8192,9216):  decb[(b*64+t)*512+h]=bf16(dec[t,b,h]); concat right half
//  blocks [9216,10240): weight transposes Wq,Wc (256 blk each), Wo (512 blk)
//  block  10240:        v2[h]=2*v[h];  Vsum = sum_h v[h]
// ---------------------------------------------------------------------------
__global__ __launch_bounds__(256)
void k_prep(const float* __restrict__ enc, const float* __restrict__ cov,
            const float* __restrict__ wcov, const float* __restrict__ dec,
            const float* __restrict__ Wq, const float* __restrict__ Wc,
            const float* __restrict__ Wo, const float* __restrict__ v,
            unsigned short* __restrict__ encpb, unsigned short* __restrict__ decb,
            unsigned short* __restrict__ concatb,
            unsigned short* __restrict__ WqT, unsigned short* __restrict__ WcT,
            unsigned short* __restrict__ WoT,
            float* __restrict__ v2, float* __restrict__ Vsum) {
  __shared__ float tile[32][33];
  const int blk = blockIdx.x, tid = threadIdx.x;

  if (blk < 8192) {
    const int idx = blk * 256 + tid;          // B*S*H
    const int h = idx & 511;
    const int bs = idx >> 9;
    const int s = bs & 511, b = bs >> 9;
    const float x = enc[(size_t)(s * BB + b) * HH + h] + cov[bs] * wcov[h];
    encpb[idx] = f2bf(fast_tanh(x));
  } else if (blk < 9216) {
    const int idx = (blk - 8192) * 256 + tid; // 512*512
    const int h = idx & 511, m = idx >> 9;    // m=b*64+t
    const int b = m >> 6, t = m & 63;
    const unsigned short val = f2bf(dec[(size_t)(t * BB + b) * HH + h]);
    decb[idx] = val;
    concatb[(size_t)m * 1024 + 512 + h] = val;
  } else if (blk < 10240) {
    int l = blk - 9216;
    const float* W; unsigned short* WT; int KT;
    if (l < 256)      { W = Wq; WT = WqT; KT = 512; }
    else if (l < 512) { W = Wc; WT = WcT; KT = 512; l -= 256; }
    else              { W = Wo; WT = WoT; KT = 1024; l -= 512; }
    const int n0 = (l & 15) * 32, k0 = (l >> 4) * 32;
    const int r = tid >> 3, c4 = (tid & 7) * 4;
    const float4 w = *(const float4*)(W + (size_t)(k0 + r) * 512 + n0 + c4);
    tile[r][c4 + 0] = w.x; tile[r][c4 + 1] = w.y;
    tile[r][c4 + 2] = w.z; tile[r][c4 + 3] = w.w;
    __syncthreads();
    unsigned short* o = WT + (size_t)(n0 + r) * KT + k0 + c4;
#pragma unroll
    for (int i = 0; i < 4; ++i) o[i] = f2bf(tile[c4 + i][r]);
  } else {
    // v2 and Vsum
    __shared__ float rb[256];
    const float va = v[tid], vb = v[tid + 256];
    v2[tid] = 2.0f * va;
    v2[tid + 256] = 2.0f * vb;
    rb[tid] = va + vb;
    __syncthreads();
    for (int off = 128; off; off >>= 1) {
      if (tid < off) rb[tid] += rb[tid + off];
      __syncthreads();
    }
    if (tid == 0) Vsum[0] = rb[0];
  }
}

// ---------------------------------------------------------------------------
// k_gemm12 — a1 and a2 GEMMs in ONE launch, epilogue writes exp(2*val):
//  blk <  64: Ea1[m,n] = exp(2*(decb@WqT + bq))     m over 512
//  blk >= 64: Ea2[m,n] = exp(2*(encpb@WcT))         m over 4096
// Tile 64x64, BK=64, 256 thr (4 waves). mfma_f32_16x16x32_bf16.
// ---------------------------------------------------------------------------
__global__ __launch_bounds__(256)
void k_gemm12(const unsigned short* __restrict__ decb,
              const unsigned short* __restrict__ encpb,
              const unsigned short* __restrict__ WqT,
              const unsigned short* __restrict__ WcT,
              const float* __restrict__ bq,
              float* __restrict__ Ea1, float* __restrict__ Ea2) {
  __shared__ unsigned short As[64][72];
  __shared__ unsigned short Bs[64][72];
  const int tid = threadIdx.x;
  const int w = tid >> 6, lane = tid & 63;

  const bool isA1 = blockIdx.x < 64;
  const int bb = isA1 ? blockIdx.x : blockIdx.x - 64;
  const int n0 = (bb & 7) * 64, m0 = (bb >> 3) * 64;
  const unsigned short* A  = isA1 ? decb : encpb;
  const unsigned short* BT = isA1 ? WqT : WcT;
  float* C = isA1 ? Ea1 : Ea2;

  f32x4 acc[4] = {};
  const int lr = tid >> 2, lk = (tid & 3) * 16;
  const int fm = w * 16 + (lane & 15);
  const int fk = (lane >> 4) * 8;

  for (int k0 = 0; k0 < 512; k0 += 64) {
    const uint4* ga = (const uint4*)(A + (size_t)(m0 + lr) * 512 + k0 + lk);
    const uint4* gb = (const uint4*)(BT + (size_t)(n0 + lr) * 512 + k0 + lk);
    uint4 a0 = ga[0], a1v = ga[1];
    uint4 b0 = gb[0], b1v = gb[1];
    *(uint4*)&As[lr][lk] = a0;
    *(uint4*)&As[lr][lk + 8] = a1v;
    *(uint4*)&Bs[lr][lk] = b0;
    *(uint4*)&Bs[lr][lk + 8] = b1v;
    __syncthreads();
#pragma unroll
    for (int ks = 0; ks < 2; ++ks) {
      bf16x8 af = *(const bf16x8*)&As[fm][ks * 32 + fk];
#pragma unroll
      for (int j = 0; j < 4; ++j) {
        bf16x8 bf = *(const bf16x8*)&Bs[j * 16 + (lane & 15)][ks * 32 + fk];
        acc[j] = __builtin_amdgcn_mfma_f32_16x16x32_bf16(af, bf, acc[j], 0, 0, 0);
      }
    }
    __syncthreads();
  }

  const int col = lane & 15, rq = lane >> 4;
#pragma unroll
  for (int j = 0; j < 4; ++j) {
    const int n = n0 + j * 16 + col;
    const float bv = isA1 ? bq[n] : 0.0f;
#pragma unroll
    for (int r = 0; r < 4; ++r) {
      const int m = m0 + w * 16 + rq * 4 + r;
      float val = acc[j][r] + bv;
      val = fminf(fmaxf(val, -30.0f), 30.0f);   // exp-safe: no inf*0 possible
      C[(size_t)m * 512 + n] = __expf(2.0f * val);
    }
  }
}

// ---------------------------------------------------------------------------
// k_scores — sc[b,t,s] = V - sum_h 2*v[h] * rcp(Ea1[b,t,h]*Ea2[b,s,h] + 1)
// ( == sum_h v[h]*tanh(a1+a2) ).  One transcendental (rcp) per element.
// Grid: 8 b (XCD-affine) x 16 t-quads x 8 s-chunks = 1024 blocks, 256 thr.
// Wave: sl=lane>>2 (16 s), hq=lane&3 (4 h-quads).
// ---------------------------------------------------------------------------
__global__ __launch_bounds__(256)
void k_scores(const float* __restrict__ Ea1, const float* __restrict__ Ea2,
              const float* __restrict__ v2g, const float* __restrict__ Vsum,
              float* __restrict__ scb) {
  const int blk = blockIdx.x;
  const int b = blk & 7, tq = (blk >> 3) & 15, sc = blk >> 7;
  const int tid = threadIdx.x;
  const int wv = tid >> 6, lane = tid & 63;
  const int hq = lane & 3, sl = lane >> 2;

  __shared__ __align__(16) float ea1s[4][HH];
  __shared__ __align__(16) float v2s[HH];

#pragma unroll
  for (int i = 0; i < 4; ++i) {
    const float* row = Ea1 + (size_t)(b * TT + tq * 4 + i) * HH;
    ea1s[i][tid] = row[tid];
    ea1s[i][tid + 256] = row[tid + 256];
  }
  v2s[tid] = v2g[tid];
  v2s[tid + 256] = v2g[tid + 256];
  __syncthreads();

  const float V = Vsum[0];
  const int s = sc * 64 + wv * 16 + sl;
  const float* erow = Ea2 + (size_t)(b * SS + s) * HH;

  float acc[4] = {0.f, 0.f, 0.f, 0.f};
#pragma unroll 4
  for (int it = 0; it < 32; ++it) {
    const int h = it * 16 + hq * 4;
    const float4 e2 = *(const float4*)(erow + h);
    const float4 vv = *(const float4*)&v2s[h];
#pragma unroll
    for (int i = 0; i < 4; ++i) {
      const float4 e1 = *(const float4*)&ea1s[i][h];
      acc[i] = fmaf(vv.x, __builtin_amdgcn_rcpf(fmaf(e1.x, e2.x, 1.0f)), acc[i]);
      acc[i] = fmaf(vv.y, __builtin_amdgcn_rcpf(fmaf(e1.y, e2.y, 1.0f)), acc[i]);
      acc[i] = fmaf(vv.z, __builtin_amdgcn_rcpf(fmaf(e1.z, e2.z, 1.0f)), acc[i]);
      acc[i] = fmaf(vv.w, __builtin_amdgcn_rcpf(fmaf(e1.w, e2.w, 1.0f)), acc[i]);
    }
  }
#pragma unroll
  for (int i = 0; i < 4; ++i) {
    acc[i] += __shfl_xor(acc[i], 1);
    acc[i] += __shfl_xor(acc[i], 2);
  }
  if (hq == 0) {
#pragma unroll
    for (int i = 0; i < 4; ++i)
      scb[(size_t)(b * TT + tq * 4 + i) * SS + s] = V - acc[i];
  }
}

// ---------------------------------------------------------------------------
// k_smctx — softmax over S per (b,t) + context, per (b, t-pair), 256 thr.
// Softmax: thread owns s=tid, s=tid+256.  Context: thread owns h=2*tid,2*tid+1
// via dword (ushort2) encp loads: 4 fma per load.
// ---------------------------------------------------------------------------
__global__ __launch_bounds__(256)
void k_smctx(const float* __restrict__ scb,
             const unsigned short* __restrict__ encpb,
             float* __restrict__ align_out,
             unsigned short* __restrict__ concatb) {
  const int b = blockIdx.x & 7;
  const int t0 = (blockIdx.x >> 3) * 2;
  const int tid = threadIdx.x;
  const int wave = tid >> 6, lane = tid & 63;

  __shared__ __align__(16) float al[2][SS];
  __shared__ float red[2][4];

  const float* r0 = scb + (size_t)(b * TT + t0) * SS;
  const float* r1 = r0 + SS;
  const float x00 = r0[tid], x01 = r0[tid + 256];
  const float x10 = r1[tid], x11 = r1[tid + 256];

  float m0 = fmaxf(x00, x01), m1 = fmaxf(x10, x11);
#pragma unroll
  for (int off = 32; off; off >>= 1) {
    m0 = fmaxf(m0, __shfl_xor(m0, off));
    m1 = fmaxf(m1, __shfl_xor(m1, off));
  }
  if (lane == 0) { red[0][wave] = m0; red[1][wave] = m1; }
  __syncthreads();
  m0 = fmaxf(fmaxf(red[0][0], red[0][1]), fmaxf(red[0][2], red[0][3]));
  m1 = fmaxf(fmaxf(red[1][0], red[1][1]), fmaxf(red[1][2], red[1][3]));
  __syncthreads();

  const float e00 = __expf(x00 - m0), e01 = __expf(x01 - m0);
  const float e10 = __expf(x10 - m1), e11 = __expf(x11 - m1);
  float s0 = e00 + e01, s1 = e10 + e11;
#pragma unroll
  for (int off = 32; off; off >>= 1) {
    s0 += __shfl_xor(s0, off);
    s1 += __shfl_xor(s1, off);
  }
  if (lane == 0) { red[0][wave] = s0; red[1][wave] = s1; }
  __syncthreads();
  s0 = red[0][0] + red[0][1] + red[0][2] + red[0][3];
  s1 = red[1][0] + red[1][1] + red[1][2] + red[1][3];
  const float rs0 = __builtin_amdgcn_rcpf(s0);
  const float rs1 = __builtin_amdgcn_rcpf(s1);

  const float a00 = e00 * rs0, a01 = e01 * rs0;
  const float a10 = e10 * rs1, a11 = e11 * rs1;
  float* ao0 = align_out + (size_t)(t0 + 0) * BB * SS + b * SS;
  float* ao1 = align_out + (size_t)(t0 + 1) * BB * SS + b * SS;
  ao0[tid] = a00; ao0[tid + 256] = a01;
  ao1[tid] = a10; ao1[tid + 256] = a11;
  al[0][tid] = a00; al[0][tid + 256] = a01;
  al[1][tid] = a10; al[1][tid + 256] = a11;
  __syncthreads();

  // context: h = 2*tid, 2*tid+1
  const unsigned* ep = (const unsigned*)(encpb + (size_t)b * SS * HH);
  float c00 = 0.f, c01 = 0.f, c10 = 0.f, c11 = 0.f;
#pragma unroll 16
  for (int s2 = 0; s2 < SS; ++s2) {
    const unsigned u = ep[s2 * 256 + tid];
    const float elo = __uint_as_float(u << 16);
    const float ehi = __uint_as_float(u & 0xffff0000u);
    const float av0 = al[0][s2], av1 = al[1][s2];
    c00 = fmaf(av0, elo, c00); c01 = fmaf(av0, ehi, c01);
    c10 = fmaf(av1, elo, c10); c11 = fmaf(av1, ehi, c11);
  }
  unsigned* cb0 = (unsigned*)(concatb + (size_t)(b * TT + t0) * 1024);
  unsigned* cb1 = (unsigned*)(concatb + (size_t)(b * TT + t0 + 1) * 1024);
  cb0[tid] = (unsigned)f2bf(c00) | ((unsigned)f2bf(c01) << 16);
  cb1[tid] = (unsigned)f2bf(c10) | ((unsigned)f2bf(c11) << 16);
}

// ---------------------------------------------------------------------------
// k_out — attn_h = [c,dec]@Wo + bo, scattered to [T,B,H]. 64x64 tiles, K=1024.
// ---------------------------------------------------------------------------
__global__ __launch_bounds__(256)
void k_out(const unsigned short* __restrict__ A,
           const unsigned short* __restrict__ BT,
           const float* __restrict__ bias, float* __restrict__ C) {
  __shared__ unsigned short As[64][72];
  __shared__ unsigned short Bs[64][72];
  const int tid = threadIdx.x;
  const int w = tid >> 6, lane = tid & 63;
  const int n0 = (blockIdx.x & 7) * 64, m0 = (blockIdx.x >> 3) * 64;

  f32x4 acc[4] = {};
  const int lr = tid >> 2, lk = (tid & 3) * 16;
  const int fm = w * 16 + (lane & 15);
  const int fk = (lane >> 4) * 8;

  for (int k0 = 0; k0 < 1024; k0 += 64) {
    const uint4* ga = (const uint4*)(A + (size_t)(m0 + lr) * 1024 + k0 + lk);
    const uint4* gb = (const uint4*)(BT + (size_t)(n0 + lr) * 1024 + k0 + lk);
    uint4 a0 = ga[0], a1v = ga[1];
    uint4 b0 = gb[0], b1v = gb[1];
    *(uint4*)&As[lr][lk] = a0;
    *(uint4*)&As[lr][lk + 8] = a1v;
    *(uint4*)&Bs[lr][lk] = b0;
    *(uint4*)&Bs[lr][lk + 8] = b1v;
    __syncthreads();
#pragma unroll
    for (int ks = 0; ks < 2; ++ks) {
      bf16x8 af = *(const bf16x8*)&As[fm][ks * 32 + fk];
#pragma unroll
      for (int j = 0; j < 4; ++j) {
        bf16x8 bf = *(const bf16x8*)&Bs[j * 16 + (lane & 15)][ks * 32 + fk];
        acc[j] = __builtin_amdgcn_mfma_f32_16x16x32_bf16(af, bf, acc[j], 0, 0, 0);
      }
    }
    __syncthreads();
  }

  const int col = lane & 15, rq = lane >> 4;
#pragma unroll
  for (int j = 0; j < 4; ++j) {
    const int n = n0 + j * 16 + col;
    const float bv = bias[n];
#pragma unroll
    for (int r = 0; r < 4; ++r) {
      const int m = m0 + w * 16 + rq * 4 + r;
      const int bi = m >> 6, t = m & 63;
      C[(size_t)(t * BB + bi) * 512 + n] = acc[j][r] + bv;
    }
  }
}

// ---------------------------------------------------------------------------
extern "C" void kernel_launch(void* const* d_in, const int* in_sizes, int n_in,
                              void* d_out, int out_size, void* d_ws, size_t ws_size,
                              hipStream_t stream) {
  const float* dec  = (const float*)d_in[0];
  const float* enc  = (const float*)d_in[1];
  const float* cov  = (const float*)d_in[2];
  const float* Wq   = (const float*)d_in[3];
  const float* bq   = (const float*)d_in[4];
  const float* Wc   = (const float*)d_in[5];
  const float* v    = (const float*)d_in[6];
  const float* Wo   = (const float*)d_in[7];
  const float* bo   = (const float*)d_in[8];
  const float* wcov = (const float*)d_in[9];

  float* out = (float*)d_out;
  float* attn_h    = out;                         // [T,B,H]
  float* align_out = out + (size_t)TT * BB * HH;  // [T,B,S]

  char* w = (char*)d_ws;
  const size_t MB = 1024 * 1024;
  unsigned short* encpb   = (unsigned short*)(w);            // 4 MB
  unsigned short* WqT     = (unsigned short*)(w + 4 * MB);   // 0.5 MB
  unsigned short* WcT     = (unsigned short*)(w + 5 * MB);   // 0.5 MB
  unsigned short* WoT     = (unsigned short*)(w + 6 * MB);   // 1 MB
  unsigned short* decb    = (unsigned short*)(w + 7 * MB);   // 0.5 MB
  unsigned short* concatb = (unsigned short*)(w + 8 * MB);   // 1 MB
  float*          Ea1     = (float*)(w + 9 * MB);            // 1 MB
  float*          Ea2     = (float*)(w + 10 * MB);           // 8 MB
  float*          scb     = (float*)(w + 18 * MB);           // 1 MB
  float*          v2      = (float*)(w + 19 * MB);           // 2 KB
  float*          Vsum    = (float*)(w + 19 * MB + 4096);    // 4 B

  k_prep<<<10241, 256, 0, stream>>>(enc, cov, wcov, dec, Wq, Wc, Wo, v,
                                    encpb, decb, concatb, WqT, WcT, WoT, v2, Vsum);
  k_gemm12<<<576, 256, 0, stream>>>(decb, encpb, WqT, WcT, bq, Ea1, Ea2);
  k_scores<<<1024, 256, 0, stream>>>(Ea1, Ea2, v2, Vsum, scb);
  k_smctx<<<256, 256, 0, stream>>>(scb, encpb, align_out, concatb);
  k_out<<<64, 256, 0, stream>>>(concatb, WoT, bo, attn_h);
}